// Round 12
// baseline (277.704 us; speedup 1.0000x reference)
//
#include <hip/hip_runtime.h>
#include <cstdint>
#include <cstddef>

#define NN 2048   // nodes
#define NE 4096   // edges
#define NG 128    // graphs
#define HD 128    // hidden
#define SKM 16    // split-K blocks layers 1-4: sk*8 h-cols each; sk=15 adds bias row
#define SK0 5     // split-K blocks layer 0
#define NCH 64    // CSR sort chunks
#define CHE 64    // edges per chunk

typedef __attribute__((ext_vector_type(8))) _Float16 f16x8;
typedef __attribute__((ext_vector_type(4))) float f32x4;

#define GLOAD_LDS16(gptr, lptr)                                                          \
  __builtin_amdgcn_global_load_lds((const __attribute__((address_space(1))) unsigned int*)(gptr), \
                                   (__attribute__((address_space(3))) unsigned int*)(lptr), 16, 0, 0)

#define VMW(n) asm volatile("s_waitcnt vmcnt(" #n ")" ::: "memory")

// ---------------- fused prep: hist + edge-MLP h + x-pad + w2T0 + w2T ----------------
__global__ __launch_bounds__(256) void k_prep(
    const float* __restrict__ ea,
    const float* __restrict__ w1_0, const float* __restrict__ b1_0,
    const float* __restrict__ w1_s, const float* __restrict__ b1_s,
    const float* __restrict__ x,
    const float* __restrict__ w2_0, const float* __restrict__ b2_0,
    const float* __restrict__ w2s, const float* __restrict__ b2s,
    const int* __restrict__ dst, int* __restrict__ hist,
    _Float16* __restrict__ hb, _Float16* __restrict__ x16,
    _Float16* __restrict__ w2T0, _Float16* __restrict__ w2T) {
  __shared__ float sld[64][65];
  const int bid = blockIdx.x, t = threadIdx.x;

  if (bid < 10240) {
    // edge MLP h for all 5 layers
    int idx = bid * 256 + t;             // l*2^19 + e*128 + c
    int c = idx & (HD - 1);
    int e = (idx >> 7) & (NE - 1);
    int l = idx >> 19;
    const float* w1 = (l == 0) ? w1_0 : (w1_s + (size_t)(l - 1) * 4 * HD);
    const float* b1 = (l == 0) ? b1_0 : (b1_s + (size_t)(l - 1) * HD);
    float4 a = *(const float4*)(ea + (size_t)e * 4);
    float v = b1[c] + a.x * w1[c] + a.y * w1[HD + c] + a.z * w1[2 * HD + c] + a.w * w1[3 * HD + c];
    hb[idx] = (_Float16)fmaxf(v, 0.f);
  } else if (bid < 10368) {
    // pad x [2048][11] f32 -> [2048][16] f16
    int idx = (bid - 10240) * 256 + t;
    int n = idx >> 4, i = idx & 15;
    x16[idx] = (_Float16)(i < 11 ? x[(size_t)n * 11 + i] : 0.f);
  } else if (bid < 10496) {
    // layer-0 weight: w2T0[o][kappa], kappa = 16k+i (i<11 valid; k=128 bias), KT0=2080
    int o = bid - 10368;
    for (int kap = t; kap < 2080; kap += 256) {
      int k = kap >> 4, i = kap & 15;
      float v = 0.f;
      if (i < 11) {
        if (k < 128) v = w2_0[(size_t)k * 1408 + i * 128 + o];
        else if (k == 128) v = b2_0[i * 128 + o];
      }
      w2T0[(size_t)o * 2080 + kap] = (_Float16)v;
    }
  } else if (bid < 12560) {
    // layers 1-4: w2T[l][o][kappa], kappa=k*128+i (<16384 w2 flat; >=16384 b2 rows)
    int idx2 = bid - 10496;              // 0..2063 = l(4) x ob(2) x kb(258)
    int l = idx2 / 516;
    int rem = idx2 - l * 516;
    int ob = rem / 258;
    int kb = rem - ob * 258;
    const float* w2 = w2s + (size_t)l * 16384 * 128;
    const float* b2 = b2s + (size_t)l * 128 * 128;
    _Float16* outp = w2T + (size_t)l * 128 * 16512;
    int k0 = kb * 64, o0 = ob * 64;
    int r = t >> 4, c4 = (t & 15) * 4;
#pragma unroll
    for (int it = 0; it < 4; ++it) {
      int kk = k0 + r + it * 16;
      const float* srcp = (kk < 16384) ? (w2 + (size_t)kk * 128 + o0 + c4)
                                       : (b2 + (size_t)(kk - 16384) * 128 + o0 + c4);
      *(float4*)&sld[r + it * 16][c4] = *(const float4*)srcp;
    }
    __syncthreads();
    int rr = t >> 3, c8 = (t & 7) * 8;
#pragma unroll
    for (int it = 0; it < 2; ++it) {
      int ol = rr + it * 32;
      _Float16 pk[8];
#pragma unroll
      for (int j = 0; j < 8; ++j) pk[j] = (_Float16)sld[c8 + j][ol];
      *(f16x8*)(outp + (size_t)(o0 + ol) * 16512 + k0 + c8) = *(const f16x8*)pk;
    }
  } else {
    // per-chunk histogram (int atomics: deterministic)
    int e = (bid - 12560) * 256 + t;
    if (e < NE) atomicAdd(&hist[(e >> 6) * NN + dst[e]], 1);
  }
}

// ---------------- scan -> rowptr + chunkoff + graph bounds ----------------
__global__ __launch_bounds__(1024) void k_scan2(const int* __restrict__ hist,
                                                int* __restrict__ rowptr,
                                                int* __restrict__ chunkoff,
                                                const int* __restrict__ batch,
                                                int* __restrict__ gstart) {
  __shared__ int s[NN];
  int t = threadIdx.x;
  int c0 = 0, c1 = 0;
  for (int c = 0; c < NCH; ++c) { c0 += hist[c * NN + t]; c1 += hist[c * NN + t + 1024]; }
  s[t] = c0; s[t + 1024] = c1;
  __syncthreads();
  for (int d = 1; d < NN; d <<= 1) {
    int a0 = s[t], a1 = s[t + 1024];
    int v0 = (t >= d) ? s[t - d] : 0;
    int v1 = (t + 1024 >= d) ? s[t + 1024 - d] : 0;
    __syncthreads();
    s[t] = a0 + v0; s[t + 1024] = a1 + v1;
    __syncthreads();
  }
  rowptr[t + 1] = s[t]; rowptr[t + 1025] = s[t + 1024];
  if (t == 0) rowptr[0] = 0;
  int run0 = s[t] - c0, run1 = s[t + 1024] - c1;   // exclusive prefix
  for (int c = 0; c < NCH; ++c) {
    chunkoff[c * NN + t] = run0;        run0 += hist[c * NN + t];
    chunkoff[c * NN + t + 1024] = run1; run1 += hist[c * NN + t + 1024];
  }
  if (t <= NG) {
    int lo = 0, hi = NN;
    while (lo < hi) { int mid = (lo + hi) >> 1; if (batch[mid] < t) lo = mid + 1; else hi = mid; }
    gstart[t] = lo;
  }
}

__global__ __launch_bounds__(64) void k_fill2(const int* __restrict__ dst,
                                              const int* __restrict__ chunkoff,
                                              int* __restrict__ elist) {
  __shared__ int sd[CHE];
  int c = blockIdx.x, t = threadIdx.x;
  int e = c * CHE + t;
  int dv = dst[e];
  sd[t] = dv;
  __syncthreads();
  int lrank = 0;
  for (int j = 0; j < t; ++j) lrank += (sd[j] == dv) ? 1 : 0;
  elist[chunkoff[c * NN + dv] + lrank] = e;   // stable order -> deterministic sums
}

// ---------------- layer-0 MFMA GEMM ----------------
__global__ __launch_bounds__(256, 2) void k_mma0(
    const _Float16* __restrict__ xh,   // [NN][16] f16
    const _Float16* __restrict__ hb,   // [NE][128] f16 (layer 0)
    const _Float16* __restrict__ w2T,  // [128][2080]
    const int* __restrict__ src,
    _Float16* __restrict__ msgp) {
  constexpr int KT = 2080;
  __shared__ _Float16 Bs[2][4096];
  __shared__ _Float16 hTl[26][128];

  const int tid = threadIdx.x;
  const int e0 = blockIdx.x * 128;
  const int w = tid >> 6, l = tid & 63, l16 = l & 15, g = l >> 4;

  const int k0 = blockIdx.y * 13, nk = 13;
  const int kb = k0 * 2;

  int nd[8];
#pragma unroll
  for (int mt = 0; mt < 8; ++mt) nd[mt] = src[e0 + mt * 16 + l16];

  for (int idx = tid; idx < 26 * 128; idx += 256) {
    int kk = idx >> 7, m = idx & 127;
    int k = kb + kk;
    _Float16 v;
    if (k < 128) v = hb[(size_t)(e0 + m) * 128 + k];
    else v = (k == 128) ? (_Float16)1.0f : (_Float16)0.0f;
    hTl[kk][m] = v;
  }

  f16x8 xr[8];
#pragma unroll
  for (int mt = 0; mt < 8; ++mt)
    xr[mt] = *(const f16x8*)(xh + (size_t)nd[mt] * 16 + (g & 1) * 8);

  auto stageB = [&](int buf, int c) {
    const int kap0 = c * 32;
#pragma unroll
    for (int j2 = 0; j2 < 2; ++j2) {
      int ntg = w * 2 + j2;
      const _Float16* gp = w2T + (size_t)(ntg * 16 + l16) * KT + kap0 + g * 8;
      GLOAD_LDS16(gp, &Bs[buf][(w * 128 + j2 * 64) * 8]);
    }
  };

  stageB(0, k0);
  __syncthreads();

  f32x4 acc[8][2];
#pragma unroll
  for (int mt = 0; mt < 8; ++mt)
#pragma unroll
    for (int jj = 0; jj < 2; ++jj) acc[mt][jj] = (f32x4){0.f, 0.f, 0.f, 0.f};

  int buf = 0;
  for (int j = 0; j < nk; ++j) {
    if (j + 1 < nk) {
      stageB(buf ^ 1, k0 + j + 1);
      asm volatile("s_waitcnt vmcnt(2)" ::: "memory");
    } else {
      asm volatile("s_waitcnt vmcnt(0)" ::: "memory");
    }
    __builtin_amdgcn_sched_barrier(0);

    f16x8 bv0 = *(const f16x8*)&Bs[buf][(size_t)(w * 2 + 0) * 512 + l * 8];
    f16x8 bv1 = *(const f16x8*)&Bs[buf][(size_t)(w * 2 + 1) * 512 + l * 8];
#pragma unroll
    for (int mt = 0; mt < 8; ++mt) {
      _Float16 hh = hTl[2 * j + (g >> 1)][mt * 16 + l16];
      f16x8 hv = {hh, hh, hh, hh, hh, hh, hh, hh};
      f16x8 av = xr[mt] * hv;
      acc[mt][0] = __builtin_amdgcn_mfma_f32_16x16x32_f16(av, bv0, acc[mt][0], 0, 0, 0);
      acc[mt][1] = __builtin_amdgcn_mfma_f32_16x16x32_f16(av, bv1, acc[mt][1], 0, 0, 0);
    }
    buf ^= 1;
    __syncthreads();
  }

  _Float16* mp = msgp + ((size_t)blockIdx.y * NE + e0) * 128;
#pragma unroll
  for (int mt = 0; mt < 8; ++mt)
#pragma unroll
    for (int jj = 0; jj < 2; ++jj)
#pragma unroll
      for (int r = 0; r < 4; ++r) {
        int row = mt * 16 + 4 * g + r;
        mp[(size_t)row * 128 + w * 32 + jj * 16 + l16] = (_Float16)acc[mt][jj][r];
      }
}

// ---------------- layers 1-4 MFMA GEMM: wave-private B, h-in-reg, zero barriers,
// XCD-pinned B slices (bid%8 == sk%8), 4-deep ring + counted vmcnt(6) ----------------
__global__ __launch_bounds__(256, 2) void k_mma4(
    const _Float16* __restrict__ xh,   // [NN][128]
    const _Float16* __restrict__ hb,   // [NE][128] (this layer)
    const _Float16* __restrict__ w2T,  // [128][16512]
    const int* __restrict__ src,
    _Float16* __restrict__ msgp) {     // [SKM][NE][128]
  constexpr int KT = 16512;
  __shared__ __align__(16) _Float16 Bs[4][4096];   // 4 x 8KB ring, wave-private quarters

  const int tid = threadIdx.x;
  const int w = tid >> 6, l = tid & 63, l16 = l & 15, g = l >> 4;
  const int bid = blockIdx.x;
  const int eb = bid >> 4, sk = bid & 15;   // bid%8 == sk%8 -> B slice pinned per XCD
  const int e0 = eb * 128;
  const int k0 = sk * 8;
  const bool haveBias = (sk == 15);

  int nd[8];
#pragma unroll
  for (int mt = 0; mt < 8; ++mt) nd[mt] = src[e0 + mt * 16 + l16];

  f16x8 hv[8];   // h[m][k0..k0+8) per M-tile row, lane-local
#pragma unroll
  for (int mt = 0; mt < 8; ++mt)
    hv[mt] = *(const f16x8*)(hb + (size_t)(e0 + mt * 16 + l16) * 128 + k0);

  auto stageB = [&](int buf, int kap0) {
#pragma unroll
    for (int j2 = 0; j2 < 2; ++j2) {
      const _Float16* gp = w2T + (size_t)((w * 2 + j2) * 16 + l16) * KT + kap0 + g * 8;
      GLOAD_LDS16(gp, &Bs[buf][(w * 2 + j2) * 512]);
    }
  };
  auto kapOf = [&](int s) { return (k0 + (s & 7)) * 128 + (s >> 3) * 32; };

  f32x4 acc[8][2];
#pragma unroll
  for (int mt = 0; mt < 8; ++mt) {
    acc[mt][0] = (f32x4){0.f, 0.f, 0.f, 0.f};
    acc[mt][1] = (f32x4){0.f, 0.f, 0.f, 0.f};
  }

  // prologue: 3 stages in flight
  stageB(0, kapOf(0));
  stageB(1, kapOf(1));
  stageB(2, kapOf(2));

#define CONSUME_S(S, AV_EXPR)                                                          \
  {                                                                                    \
    const int buf_ = (S) & 3;                                                          \
    f16x8 bv0 = *(const f16x8*)&Bs[buf_][(w * 2 + 0) * 512 + l * 8];                   \
    f16x8 bv1 = *(const f16x8*)&Bs[buf_][(w * 2 + 1) * 512 + l * 8];                   \
    _Pragma("unroll")                                                                  \
    for (int mt = 0; mt < 8; ++mt) {                                                   \
      f16x8 av = (AV_EXPR);                                                            \
      acc[mt][0] = __builtin_amdgcn_mfma_f32_16x16x32_f16(av, bv0, acc[mt][0], 0, 0, 0); \
      acc[mt][1] = __builtin_amdgcn_mfma_f32_16x16x32_f16(av, bv1, acc[mt][1], 0, 0, 0); \
    }                                                                                  \
  }

#pragma unroll
  for (int win = 0; win < 4; ++win) {
    f16x8 xw[8];
#pragma unroll
    for (int mt = 0; mt < 8; ++mt)
      xw[mt] = *(const f16x8*)(xh + (size_t)nd[mt] * 128 + win * 32 + g * 8);

#pragma unroll
    for (int jk = 0; jk < 8; ++jk) {
      const int s = win * 8 + jk;
      const int nxt = s + 3;
      if (nxt < 32) {
        stageB(nxt & 3, kapOf(nxt));
        VMW(6);
      } else if (haveBias) {
        stageB(nxt & 3, 16384 + (nxt - 32) * 32);   // bias rows kappa=16384+i (stages 32..34)
        VMW(6);
      } else {
        if (nxt == 32) { VMW(4); }
        else if (nxt == 33) { VMW(2); }
        else { VMW(0); }
      }
      __builtin_amdgcn_sched_barrier(0);
      _Float16 hh;
      CONSUME_S(s, ({ hh = hv[mt][jk];
                      f16x8 hs = {hh, hh, hh, hh, hh, hh, hh, hh};
                      xw[mt] * hs; }));
    }
  }

  if (haveBias) {   // 4 bias steps (h == 1), bufs (32..35)&3, simple drain
    stageB(3, 16384 + 3 * 32);   // FIX R12: stage 35 (bias i-window 3) was never issued
                                 // in the win loop; buf3 is free after s=31's consume.
#pragma unroll
    for (int b = 0; b < 4; ++b) {
      f16x8 xb[8];
#pragma unroll
      for (int mt = 0; mt < 8; ++mt)
        xb[mt] = *(const f16x8*)(xh + (size_t)nd[mt] * 128 + b * 32 + g * 8);
      VMW(0);
      __builtin_amdgcn_sched_barrier(0);
      CONSUME_S(32 + b, (xb[mt]));
    }
  }
#undef CONSUME_S

  // epilogue: C/D row = 4g + r, col = l16
  _Float16* mp = msgp + ((size_t)sk * NE + e0) * 128;
#pragma unroll
  for (int mt = 0; mt < 8; ++mt)
#pragma unroll
    for (int jj = 0; jj < 2; ++jj)
#pragma unroll
      for (int r = 0; r < 4; ++r) {
        int row = mt * 16 + 4 * g + r;
        mp[(size_t)row * 128 + w * 32 + jj * 16 + l16] = (_Float16)acc[mt][jj][r];
      }
}

// ---------------- dense split-K reduce msgp[SK][NE][HD] -> msgf f32 [NE][HD] ----------------
template <int NSK>
__global__ __launch_bounds__(256) void k_msum(const _Float16* __restrict__ msgp,
                                              float* __restrict__ msgf) {
  int idx = blockIdx.x * 256 + threadIdx.x;   // 65536 threads, 8 cols each
  const _Float16* p = msgp + (size_t)idx * 8;
  float s0 = 0.f, s1 = 0.f, s2 = 0.f, s3 = 0.f, s4 = 0.f, s5 = 0.f, s6 = 0.f, s7 = 0.f;
#pragma unroll
  for (int k = 0; k < NSK; ++k) {
    f16x8 v = *(const f16x8*)(p + (size_t)k * NE * HD);
    s0 += (float)v[0]; s1 += (float)v[1]; s2 += (float)v[2]; s3 += (float)v[3];
    s4 += (float)v[4]; s5 += (float)v[5]; s6 += (float)v[6]; s7 += (float)v[7];
  }
  float4* o = (float4*)(msgf + (size_t)idx * 8);
  o[0] = (float4){s0, s1, s2, s3};
  o[1] = (float4){s4, s5, s6, s7};
}

// ---------------- scatter-mean (1 f32 load/edge) + root + BN + ReLU (+res) ----------------
template <int INR>
__global__ void k_au(const float* __restrict__ msgf, const int* __restrict__ rowptr,
                     const int* __restrict__ elist, const float* __restrict__ xin,
                     const float* __restrict__ root, const float* __restrict__ bias,
                     const float* __restrict__ bg, const float* __restrict__ bb,
                     const float* __restrict__ bm, const float* __restrict__ bv,
                     const float* __restrict__ h_prev, float* __restrict__ h_out,
                     _Float16* __restrict__ h_out_h) {
  int n = blockIdx.x, t = threadIdx.x;  // 128 threads
  __shared__ float xr[INR];
  if (t < INR) xr[t] = xin[(size_t)n * INR + t];
  int beg = rowptr[n], end = rowptr[n + 1];
  float v = 0.f;
  for (int j = beg; j < end; ++j) v += msgf[(size_t)elist[j] * HD + t];
  v /= fmaxf((float)(end - beg), 1.f);
  __syncthreads();
  float acc = v + bias[t];
  if constexpr (INR == 128) {
    float a0 = 0.f, a1 = 0.f, a2 = 0.f, a3 = 0.f;
#pragma unroll 4
    for (int k = 0; k < 128; k += 4) {
      a0 += xr[k + 0] * root[(size_t)(k + 0) * HD + t];
      a1 += xr[k + 1] * root[(size_t)(k + 1) * HD + t];
      a2 += xr[k + 2] * root[(size_t)(k + 2) * HD + t];
      a3 += xr[k + 3] * root[(size_t)(k + 3) * HD + t];
    }
    acc += (a0 + a1) + (a2 + a3);
  } else {
#pragma unroll
    for (int k = 0; k < INR; ++k) acc += xr[k] * root[(size_t)k * HD + t];
  }
  float bn = (acc - bm[t]) * rsqrtf(bv[t] + 1e-5f) * bg[t] + bb[t];
  float r = fmaxf(bn, 0.f);
  float val = h_prev ? (h_prev[(size_t)n * HD + t] + r) : r;
  h_out[(size_t)n * HD + t] = val;
  h_out_h[(size_t)n * HD + t] = (_Float16)val;
}

// ---------------- fused global mean pool + readout MLP ----------------
__global__ void k_poolread(const float* __restrict__ h, const int* __restrict__ gstart,
                           const float* __restrict__ w1, const float* __restrict__ b1,
                           const float* __restrict__ w2, const float* __restrict__ b2,
                           float* __restrict__ out) {
  int g = blockIdx.x, t = threadIdx.x;  // 128 threads
  __shared__ float row[HD];
  int beg = gstart[g], end = gstart[g + 1];
  float v = 0.f;
  for (int n = beg; n < end; ++n) v += h[(size_t)n * HD + t];
  row[t] = v / fmaxf((float)(end - beg), 1.f);
  __syncthreads();
  if (t < 64) {
    float acc = b1[t];
#pragma unroll 8
    for (int k = 0; k < HD; ++k) acc += row[k] * w1[(size_t)k * 64 + t];
    float vv = fmaxf(acc, 0.f) * w2[t];
#pragma unroll
    for (int off = 32; off > 0; off >>= 1) vv += __shfl_down(vv, off);
    if (t == 0) out[g] = vv + b2[0];
  }
}

extern "C" void kernel_launch(void* const* d_in, const int* in_sizes, int n_in,
                              void* d_out, int out_size, void* d_ws, size_t ws_size,
                              hipStream_t stream) {
  const float* x      = (const float*)d_in[0];
  const float* ea     = (const float*)d_in[1];
  const int*   eidx   = (const int*)d_in[2];
  const int*   batch  = (const int*)d_in[3];
  const float* w1_0   = (const float*)d_in[4];
  const float* b1_0   = (const float*)d_in[5];
  const float* w2_0   = (const float*)d_in[6];
  const float* b2_0   = (const float*)d_in[7];
  const float* root_0 = (const float*)d_in[8];
  const float* bias_0 = (const float*)d_in[9];
  const float* bn_g0  = (const float*)d_in[10];
  const float* bn_b0  = (const float*)d_in[11];
  const float* bn_m0  = (const float*)d_in[12];
  const float* bn_v0  = (const float*)d_in[13];
  const float* w1_s   = (const float*)d_in[14];
  const float* b1_s   = (const float*)d_in[15];
  const float* w2_s   = (const float*)d_in[16];
  const float* b2_s   = (const float*)d_in[17];
  const float* root_s = (const float*)d_in[18];
  const float* bias_s = (const float*)d_in[19];
  const float* bn_gs  = (const float*)d_in[20];
  const float* bn_bs  = (const float*)d_in[21];
  const float* bn_ms  = (const float*)d_in[22];
  const float* bn_vs  = (const float*)d_in[23];
  const float* lin1_w = (const float*)d_in[24];
  const float* lin1_b = (const float*)d_in[25];
  const float* lin2_w = (const float*)d_in[26];
  const float* lin2_b = (const float*)d_in[27];
  float* out = (float*)d_out;

  char* wsb = (char*)d_ws;
  size_t off = 0;
  auto alloc = [&](size_t bytes) { void* p = wsb + off; off = (off + bytes + 255) & ~(size_t)255; return p; };
  int*      rowptr   = (int*)alloc((NN + 4) * 4);
  int*      elist    = (int*)alloc(NE * 4);
  int*      gstart   = (int*)alloc((NG + 4) * 4);
  int*      hist     = (int*)alloc((size_t)NCH * NN * 4);
  int*      chunkoff = (int*)alloc((size_t)NCH * NN * 4);
  _Float16* hbf      = (_Float16*)alloc((size_t)5 * NE * HD * 2);
  _Float16* x16      = (_Float16*)alloc((size_t)NN * 16 * 2);
  _Float16* w2T0     = (_Float16*)alloc((size_t)128 * 2080 * 2);
  _Float16* w2T      = (_Float16*)alloc((size_t)4 * 128 * 16512 * 2);
  float*    hnA      = (float*)alloc((size_t)NN * HD * 4);
  float*    hnB      = (float*)alloc((size_t)NN * HD * 4);
  _Float16* hnAh     = (_Float16*)alloc((size_t)NN * HD * 2);
  _Float16* hnBh     = (_Float16*)alloc((size_t)NN * HD * 2);
  _Float16* msgp     = (_Float16*)alloc((size_t)SKM * NE * HD * 2);
  float*    msgf     = (float*)alloc((size_t)NE * HD * 4);

  const int* src = eidx;
  const int* dstp = eidx + NE;

  hipMemsetAsync(hist, 0, (size_t)NCH * NN * 4, stream);
  k_prep<<<dim3(12576), 256, 0, stream>>>(ea, w1_0, b1_0, w1_s, b1_s, x,
                                          w2_0, b2_0, w2_s, b2_s,
                                          dstp, hist, hbf, x16, w2T0, w2T);
  k_scan2<<<1, 1024, 0, stream>>>(hist, rowptr, chunkoff, batch, gstart);
  k_fill2<<<dim3(NCH), 64, 0, stream>>>(dstp, chunkoff, elist);

  // layer 0
  k_mma0<<<dim3(NE / 128, SK0), 256, 0, stream>>>(x16, hbf, w2T0, src, msgp);
  k_msum<SK0><<<dim3(256), 256, 0, stream>>>(msgp, msgf);
  k_au<11><<<NN, HD, 0, stream>>>(msgf, rowptr, elist, x, root_0, bias_0,
                                  bn_g0, bn_b0, bn_m0, bn_v0, nullptr, hnA, hnAh);

  float* cur = hnA;  _Float16* curh = hnAh;
  float* nxt = hnB;  _Float16* nxth = hnBh;
  for (int l = 1; l <= 4; ++l) {
    const _Float16* w2Tl = w2T + (size_t)(l - 1) * 128 * 16512;
    k_mma4<<<dim3((NE / 128) * SKM), 256, 0, stream>>>(curh, hbf + (size_t)l * NE * HD,
                                                       w2Tl, src, msgp);
    k_msum<SKM><<<dim3(256), 256, 0, stream>>>(msgp, msgf);
    k_au<128><<<NN, HD, 0, stream>>>(msgf, rowptr, elist, cur,
                                     root_s + (size_t)(l - 1) * HD * HD,
                                     bias_s + (size_t)(l - 1) * HD,
                                     bn_gs + (size_t)(l - 1) * HD, bn_bs + (size_t)(l - 1) * HD,
                                     bn_ms + (size_t)(l - 1) * HD, bn_vs + (size_t)(l - 1) * HD,
                                     cur, nxt, nxth);
    float* tf = cur; cur = nxt; nxt = tf;
    _Float16* th = curh; curh = nxth; nxth = th;
  }

  k_poolread<<<NG, HD, 0, stream>>>(cur, gstart, lin1_w, lin1_b, lin2_w, lin2_b, out);
}

// Round 13
// 232.145 us; speedup vs baseline: 1.1963x; 1.1963x over previous
//
#include <hip/hip_runtime.h>
#include <cstdint>
#include <cstddef>

#define NN 2048   // nodes
#define NE 4096   // edges
#define NG 128    // graphs
#define HD 128    // hidden
#define SKM 16    // split-K blocks layers 1-4 (129 h-cols: 9 + 15x8)
#define SK0 5     // split-K blocks layer 0
#define NCH 64    // CSR sort chunks
#define CHE 64    // edges per chunk

typedef __attribute__((ext_vector_type(8))) _Float16 f16x8;
typedef __attribute__((ext_vector_type(4))) float f32x4;

#define GLOAD_LDS16(gptr, lptr)                                                          \
  __builtin_amdgcn_global_load_lds((const __attribute__((address_space(1))) unsigned int*)(gptr), \
                                   (__attribute__((address_space(3))) unsigned int*)(lptr), 16, 0, 0)

// ---------------- fused prep: hist + edge-MLP h + x-pad + w2T0 + w2T (R5 verbatim) ----------------
__global__ __launch_bounds__(256) void k_prep(
    const float* __restrict__ ea,
    const float* __restrict__ w1_0, const float* __restrict__ b1_0,
    const float* __restrict__ w1_s, const float* __restrict__ b1_s,
    const float* __restrict__ x,
    const float* __restrict__ w2_0, const float* __restrict__ b2_0,
    const float* __restrict__ w2s, const float* __restrict__ b2s,
    const int* __restrict__ dst, int* __restrict__ hist,
    _Float16* __restrict__ hb, _Float16* __restrict__ x16,
    _Float16* __restrict__ w2T0, _Float16* __restrict__ w2T) {
  __shared__ float sld[64][65];
  const int bid = blockIdx.x, t = threadIdx.x;

  if (bid < 10240) {
    // edge MLP h for all 5 layers
    int idx = bid * 256 + t;             // l*2^19 + e*128 + c
    int c = idx & (HD - 1);
    int e = (idx >> 7) & (NE - 1);
    int l = idx >> 19;
    const float* w1 = (l == 0) ? w1_0 : (w1_s + (size_t)(l - 1) * 4 * HD);
    const float* b1 = (l == 0) ? b1_0 : (b1_s + (size_t)(l - 1) * HD);
    float4 a = *(const float4*)(ea + (size_t)e * 4);
    float v = b1[c] + a.x * w1[c] + a.y * w1[HD + c] + a.z * w1[2 * HD + c] + a.w * w1[3 * HD + c];
    hb[idx] = (_Float16)fmaxf(v, 0.f);
  } else if (bid < 10368) {
    // pad x [2048][11] f32 -> [2048][16] f16
    int idx = (bid - 10240) * 256 + t;
    int n = idx >> 4, i = idx & 15;
    x16[idx] = (_Float16)(i < 11 ? x[(size_t)n * 11 + i] : 0.f);
  } else if (bid < 10496) {
    // layer-0 weight: w2T0[o][kappa], kappa = 16k+i (i<11 valid; k=128 bias), KT0=2080
    int o = bid - 10368;
    for (int kap = t; kap < 2080; kap += 256) {
      int k = kap >> 4, i = kap & 15;
      float v = 0.f;
      if (i < 11) {
        if (k < 128) v = w2_0[(size_t)k * 1408 + i * 128 + o];
        else if (k == 128) v = b2_0[i * 128 + o];
      }
      w2T0[(size_t)o * 2080 + kap] = (_Float16)v;
    }
  } else if (bid < 12560) {
    // layers 1-4: w2T[l][o][kappa], kappa=k*128+i (<16384 w2 flat; >=16384 b2 rows)
    int idx2 = bid - 10496;              // 0..2063 = l(4) x ob(2) x kb(258)
    int l = idx2 / 516;
    int rem = idx2 - l * 516;
    int ob = rem / 258;
    int kb = rem - ob * 258;
    const float* w2 = w2s + (size_t)l * 16384 * 128;
    const float* b2 = b2s + (size_t)l * 128 * 128;
    _Float16* outp = w2T + (size_t)l * 128 * 16512;
    int k0 = kb * 64, o0 = ob * 64;
    int r = t >> 4, c4 = (t & 15) * 4;
#pragma unroll
    for (int it = 0; it < 4; ++it) {
      int kk = k0 + r + it * 16;
      const float* srcp = (kk < 16384) ? (w2 + (size_t)kk * 128 + o0 + c4)
                                       : (b2 + (size_t)(kk - 16384) * 128 + o0 + c4);
      *(float4*)&sld[r + it * 16][c4] = *(const float4*)srcp;
    }
    __syncthreads();
    int rr = t >> 3, c8 = (t & 7) * 8;
#pragma unroll
    for (int it = 0; it < 2; ++it) {
      int ol = rr + it * 32;
      _Float16 pk[8];
#pragma unroll
      for (int j = 0; j < 8; ++j) pk[j] = (_Float16)sld[c8 + j][ol];
      *(f16x8*)(outp + (size_t)(o0 + ol) * 16512 + k0 + c8) = *(const f16x8*)pk;
    }
  } else {
    // per-chunk histogram (int atomics: deterministic)
    int e = (bid - 12560) * 256 + t;
    if (e < NE) atomicAdd(&hist[(e >> 6) * NN + dst[e]], 1);
  }
}

// ---------------- scan -> rowptr + chunkoff + graph bounds (R5 verbatim) ----------------
__global__ __launch_bounds__(1024) void k_scan2(const int* __restrict__ hist,
                                                int* __restrict__ rowptr,
                                                int* __restrict__ chunkoff,
                                                const int* __restrict__ batch,
                                                int* __restrict__ gstart) {
  __shared__ int s[NN];
  int t = threadIdx.x;
  int c0 = 0, c1 = 0;
  for (int c = 0; c < NCH; ++c) { c0 += hist[c * NN + t]; c1 += hist[c * NN + t + 1024]; }
  s[t] = c0; s[t + 1024] = c1;
  __syncthreads();
  for (int d = 1; d < NN; d <<= 1) {
    int a0 = s[t], a1 = s[t + 1024];
    int v0 = (t >= d) ? s[t - d] : 0;
    int v1 = (t + 1024 >= d) ? s[t + 1024 - d] : 0;
    __syncthreads();
    s[t] = a0 + v0; s[t + 1024] = a1 + v1;
    __syncthreads();
  }
  rowptr[t + 1] = s[t]; rowptr[t + 1025] = s[t + 1024];
  if (t == 0) rowptr[0] = 0;
  int run0 = s[t] - c0, run1 = s[t + 1024] - c1;   // exclusive prefix
  for (int c = 0; c < NCH; ++c) {
    chunkoff[c * NN + t] = run0;        run0 += hist[c * NN + t];
    chunkoff[c * NN + t + 1024] = run1; run1 += hist[c * NN + t + 1024];
  }
  if (t <= NG) {
    int lo = 0, hi = NN;
    while (lo < hi) { int mid = (lo + hi) >> 1; if (batch[mid] < t) lo = mid + 1; else hi = mid; }
    gstart[t] = lo;
  }
}

__global__ __launch_bounds__(64) void k_fill2(const int* __restrict__ dst,
                                              const int* __restrict__ chunkoff,
                                              int* __restrict__ elist) {
  __shared__ int sd[CHE];
  int c = blockIdx.x, t = threadIdx.x;
  int e = c * CHE + t;
  int dv = dst[e];
  sd[t] = dv;
  __syncthreads();
  int lrank = 0;
  for (int j = 0; j < t; ++j) lrank += (sd[j] == dv) ? 1 : 0;
  elist[chunkoff[c * NN + dv] + lrank] = e;   // stable order -> deterministic sums
}

// ---------------- layer-0 MFMA GEMM (R5 verbatim) ----------------
__global__ __launch_bounds__(256, 2) void k_mma0(
    const _Float16* __restrict__ xh,   // [NN][16] f16
    const _Float16* __restrict__ hb,   // [NE][128] f16 (layer 0)
    const _Float16* __restrict__ w2T,  // [128][2080]
    const int* __restrict__ src,
    _Float16* __restrict__ msgp) {
  constexpr int KT = 2080;
  __shared__ _Float16 Bs[2][4096];
  __shared__ _Float16 hTl[26][128];

  const int tid = threadIdx.x;
  const int e0 = blockIdx.x * 128;
  const int w = tid >> 6, l = tid & 63, l16 = l & 15, g = l >> 4;

  const int k0 = blockIdx.y * 13, nk = 13;
  const int kb = k0 * 2;

  int nd[8];
#pragma unroll
  for (int mt = 0; mt < 8; ++mt) nd[mt] = src[e0 + mt * 16 + l16];

  for (int idx = tid; idx < 26 * 128; idx += 256) {
    int kk = idx >> 7, m = idx & 127;
    int k = kb + kk;
    _Float16 v;
    if (k < 128) v = hb[(size_t)(e0 + m) * 128 + k];
    else v = (k == 128) ? (_Float16)1.0f : (_Float16)0.0f;
    hTl[kk][m] = v;
  }

  f16x8 xr[8];
#pragma unroll
  for (int mt = 0; mt < 8; ++mt)
    xr[mt] = *(const f16x8*)(xh + (size_t)nd[mt] * 16 + (g & 1) * 8);

  auto stageB = [&](int buf, int c) {
    const int kap0 = c * 32;
#pragma unroll
    for (int j2 = 0; j2 < 2; ++j2) {
      int ntg = w * 2 + j2;
      const _Float16* gp = w2T + (size_t)(ntg * 16 + l16) * KT + kap0 + g * 8;
      GLOAD_LDS16(gp, &Bs[buf][(w * 128 + j2 * 64) * 8]);
    }
  };

  stageB(0, k0);
  __syncthreads();

  f32x4 acc[8][2];
#pragma unroll
  for (int mt = 0; mt < 8; ++mt)
#pragma unroll
    for (int jj = 0; jj < 2; ++jj) acc[mt][jj] = (f32x4){0.f, 0.f, 0.f, 0.f};

  int buf = 0;
  for (int j = 0; j < nk; ++j) {
    if (j + 1 < nk) {
      stageB(buf ^ 1, k0 + j + 1);
      asm volatile("s_waitcnt vmcnt(2)" ::: "memory");
    } else {
      asm volatile("s_waitcnt vmcnt(0)" ::: "memory");
    }
    __builtin_amdgcn_sched_barrier(0);

    f16x8 bv0 = *(const f16x8*)&Bs[buf][(size_t)(w * 2 + 0) * 512 + l * 8];
    f16x8 bv1 = *(const f16x8*)&Bs[buf][(size_t)(w * 2 + 1) * 512 + l * 8];
#pragma unroll
    for (int mt = 0; mt < 8; ++mt) {
      _Float16 hh = hTl[2 * j + (g >> 1)][mt * 16 + l16];
      f16x8 hv = {hh, hh, hh, hh, hh, hh, hh, hh};
      f16x8 av = xr[mt] * hv;
      acc[mt][0] = __builtin_amdgcn_mfma_f32_16x16x32_f16(av, bv0, acc[mt][0], 0, 0, 0);
      acc[mt][1] = __builtin_amdgcn_mfma_f32_16x16x32_f16(av, bv1, acc[mt][1], 0, 0, 0);
    }
    buf ^= 1;
    __syncthreads();
  }

  _Float16* mp = msgp + ((size_t)blockIdx.y * NE + e0) * 128;
#pragma unroll
  for (int mt = 0; mt < 8; ++mt)
#pragma unroll
    for (int jj = 0; jj < 2; ++jj)
#pragma unroll
      for (int r = 0; r < 4; ++r) {
        int row = mt * 16 + 4 * g + r;
        mp[(size_t)row * 128 + w * 32 + jj * 16 + l16] = (_Float16)acc[mt][jj][r];
      }
}

// ---------------- layers 1-4 MFMA GEMM: BM=256, shared 4-buf staging (R5 verbatim) ----------------
__global__ __launch_bounds__(512, 2) void k_mma3(
    const _Float16* __restrict__ xh,   // [NN][128]
    const _Float16* __restrict__ hb,   // [NE][128] (this layer)
    const _Float16* __restrict__ w2T,  // [128][16512]
    const int* __restrict__ src,
    _Float16* __restrict__ msgp) {     // [SK][NE][128]
  constexpr int KT = 16512;
  __shared__ __align__(16) _Float16 Bs[4][4096];
  __shared__ _Float16 hTl[9][256];

  const int tid = threadIdx.x;
  const int w = tid >> 6, l = tid & 63, l16 = l & 15, g = l >> 4;
  const int bid = blockIdx.x;
  const int eb = bid >> 4, sk = bid & 15;
  const int e0 = eb * 256;
  const int mg = w & 3, ng = w >> 2;

  int k0, nk;
  if (sk == 0) { k0 = 0; nk = 9; } else { k0 = 9 + (sk - 1) * 8; nk = 8; }
  const int nsteps = nk * 4;

  auto stageB = [&](int s) {
    const int jk = s >> 2, win = s & 3;
    const int kap0 = (k0 + jk) * 128 + win * 32;
    const _Float16* gp = w2T + (size_t)(w * 16 + l16) * KT + kap0 + g * 8;
    GLOAD_LDS16(gp, &Bs[s & 3][w * 512]);
  };

  stageB(0);
  stageB(1);

  int nd[4];
#pragma unroll
  for (int mt = 0; mt < 4; ++mt) nd[mt] = src[e0 + mg * 64 + mt * 16 + l16];
  f16x8 xw[4][4];
#pragma unroll
  for (int mt = 0; mt < 4; ++mt)
#pragma unroll
    for (int win = 0; win < 4; ++win)
      xw[mt][win] = *(const f16x8*)(xh + (size_t)nd[mt] * 128 + win * 32 + g * 8);

  for (int idx = tid; idx < nk * 256; idx += 512) {
    int jk = idx >> 8, m = idx & 255;
    int k = k0 + jk;
    hTl[jk][m] = (k < 128) ? hb[(size_t)(e0 + m) * 128 + k]
                           : (_Float16)(k == 128 ? 1.0f : 0.0f);
  }
  __syncthreads();   // hTl ready; prologue stages drained

  f32x4 acc[4][4];
#pragma unroll
  for (int mt = 0; mt < 4; ++mt)
#pragma unroll
    for (int j2 = 0; j2 < 4; ++j2) acc[mt][j2] = (f32x4){0.f, 0.f, 0.f, 0.f};

  for (int jk = 0; jk < nk; ++jk) {
    _Float16 hv[4];
#pragma unroll
    for (int mt = 0; mt < 4; ++mt) hv[mt] = hTl[jk][mg * 64 + mt * 16 + l16];
#pragma unroll
    for (int win = 0; win < 4; ++win) {
      const int s = jk * 4 + win;
      if (s + 2 < nsteps) {
        stageB(s + 2);
        asm volatile("s_waitcnt vmcnt(2)" ::: "memory");
      } else if (s + 2 == nsteps) {
        asm volatile("s_waitcnt vmcnt(1)" ::: "memory");
      } else {
        asm volatile("s_waitcnt vmcnt(0)" ::: "memory");
      }
      __builtin_amdgcn_s_barrier();

      const _Float16* bp = &Bs[win][ng * 2048 + g * 128 + l16 * 8];
      f16x8 bv0 = *(const f16x8*)(bp);
      f16x8 bv1 = *(const f16x8*)(bp + 512);
      f16x8 bv2 = *(const f16x8*)(bp + 1024);
      f16x8 bv3 = *(const f16x8*)(bp + 1536);
#pragma unroll
      for (int mt = 0; mt < 4; ++mt) {
        _Float16 hh = hv[mt];
        f16x8 hs = {hh, hh, hh, hh, hh, hh, hh, hh};
        f16x8 av = xw[mt][win] * hs;
        acc[mt][0] = __builtin_amdgcn_mfma_f32_16x16x32_f16(av, bv0, acc[mt][0], 0, 0, 0);
        acc[mt][1] = __builtin_amdgcn_mfma_f32_16x16x32_f16(av, bv1, acc[mt][1], 0, 0, 0);
        acc[mt][2] = __builtin_amdgcn_mfma_f32_16x16x32_f16(av, bv2, acc[mt][2], 0, 0, 0);
        acc[mt][3] = __builtin_amdgcn_mfma_f32_16x16x32_f16(av, bv3, acc[mt][3], 0, 0, 0);
      }
    }
  }

  // epilogue: C/D row = 4g + r, col = l16
  _Float16* mp = msgp + ((size_t)sk * NE + e0) * 128;
#pragma unroll
  for (int mt = 0; mt < 4; ++mt)
#pragma unroll
    for (int j2 = 0; j2 < 4; ++j2)
#pragma unroll
      for (int r = 0; r < 4; ++r) {
        int row = mg * 64 + mt * 16 + 4 * g + r;
        int col = (ng * 4 + j2) * 16 + l16;
        mp[(size_t)row * 128 + col] = (_Float16)acc[mt][j2][r];
      }
}

// ---------------- fused: split-K reduce + scatter-mean + root + BN + ReLU (+res) ----------------
// R5 structure; single delta: 4-way ILP on the INR==128 root product (validated in R8/R12).
template <int INR, int NSK>
__global__ void k_au(const _Float16* __restrict__ msgp, const int* __restrict__ rowptr,
                     const int* __restrict__ elist, const float* __restrict__ xin,
                     const float* __restrict__ root, const float* __restrict__ bias,
                     const float* __restrict__ bg, const float* __restrict__ bb,
                     const float* __restrict__ bm, const float* __restrict__ bv,
                     const float* __restrict__ h_prev, float* __restrict__ h_out,
                     _Float16* __restrict__ h_out_h) {
  int n = blockIdx.x, t = threadIdx.x;  // 128 threads
  __shared__ float xr[INR];
  if (t < INR) xr[t] = xin[(size_t)n * INR + t];
  int beg = rowptr[n], end = rowptr[n + 1];
  float v = 0.f;
  for (int j = beg; j < end; ++j) {
    int e = elist[j];
#pragma unroll
    for (int s = 0; s < NSK; ++s) v += (float)msgp[((size_t)s * NE + e) * HD + t];
  }
  v /= fmaxf((float)(end - beg), 1.f);
  __syncthreads();
  float acc = v + bias[t];
  if constexpr (INR == 128) {
    float a0 = 0.f, a1 = 0.f, a2 = 0.f, a3 = 0.f;
#pragma unroll 4
    for (int k = 0; k < 128; k += 4) {
      a0 += xr[k + 0] * root[(size_t)(k + 0) * HD + t];
      a1 += xr[k + 1] * root[(size_t)(k + 1) * HD + t];
      a2 += xr[k + 2] * root[(size_t)(k + 2) * HD + t];
      a3 += xr[k + 3] * root[(size_t)(k + 3) * HD + t];
    }
    acc += (a0 + a1) + (a2 + a3);
  } else {
#pragma unroll
    for (int k = 0; k < INR; ++k) acc += xr[k] * root[(size_t)k * HD + t];
  }
  float bn = (acc - bm[t]) * rsqrtf(bv[t] + 1e-5f) * bg[t] + bb[t];
  float r = fmaxf(bn, 0.f);
  float val = h_prev ? (h_prev[(size_t)n * HD + t] + r) : r;
  h_out[(size_t)n * HD + t] = val;
  h_out_h[(size_t)n * HD + t] = (_Float16)val;
}

// ---------------- fused global mean pool + readout MLP ----------------
__global__ void k_poolread(const float* __restrict__ h, const int* __restrict__ gstart,
                           const float* __restrict__ w1, const float* __restrict__ b1,
                           const float* __restrict__ w2, const float* __restrict__ b2,
                           float* __restrict__ out) {
  int g = blockIdx.x, t = threadIdx.x;  // 128 threads
  __shared__ float row[HD];
  int beg = gstart[g], end = gstart[g + 1];
  float v = 0.f;
  for (int n = beg; n < end; ++n) v += h[(size_t)n * HD + t];
  row[t] = v / fmaxf((float)(end - beg), 1.f);
  __syncthreads();
  if (t < 64) {
    float acc = b1[t];
#pragma unroll 8
    for (int k = 0; k < HD; ++k) acc += row[k] * w1[(size_t)k * 64 + t];
    float vv = fmaxf(acc, 0.f) * w2[t];
#pragma unroll
    for (int off = 32; off > 0; off >>= 1) vv += __shfl_down(vv, off);
    if (t == 0) out[g] = vv + b2[0];
  }
}

extern "C" void kernel_launch(void* const* d_in, const int* in_sizes, int n_in,
                              void* d_out, int out_size, void* d_ws, size_t ws_size,
                              hipStream_t stream) {
  const float* x      = (const float*)d_in[0];
  const float* ea     = (const float*)d_in[1];
  const int*   eidx   = (const int*)d_in[2];
  const int*   batch  = (const int*)d_in[3];
  const float* w1_0   = (const float*)d_in[4];
  const float* b1_0   = (const float*)d_in[5];
  const float* w2_0   = (const float*)d_in[6];
  const float* b2_0   = (const float*)d_in[7];
  const float* root_0 = (const float*)d_in[8];
  const float* bias_0 = (const float*)d_in[9];
  const float* bn_g0  = (const float*)d_in[10];
  const float* bn_b0  = (const float*)d_in[11];
  const float* bn_m0  = (const float*)d_in[12];
  const float* bn_v0  = (const float*)d_in[13];
  const float* w1_s   = (const float*)d_in[14];
  const float* b1_s   = (const float*)d_in[15];
  const float* w2_s   = (const float*)d_in[16];
  const float* b2_s   = (const float*)d_in[17];
  const float* root_s = (const float*)d_in[18];
  const float* bias_s = (const float*)d_in[19];
  const float* bn_gs  = (const float*)d_in[20];
  const float* bn_bs  = (const float*)d_in[21];
  const float* bn_ms  = (const float*)d_in[22];
  const float* bn_vs  = (const float*)d_in[23];
  const float* lin1_w = (const float*)d_in[24];
  const float* lin1_b = (const float*)d_in[25];
  const float* lin2_w = (const float*)d_in[26];
  const float* lin2_b = (const float*)d_in[27];
  float* out = (float*)d_out;

  char* wsb = (char*)d_ws;
  size_t off = 0;
  auto alloc = [&](size_t bytes) { void* p = wsb + off; off = (off + bytes + 255) & ~(size_t)255; return p; };
  int*      rowptr   = (int*)alloc((NN + 4) * 4);
  int*      elist    = (int*)alloc(NE * 4);
  int*      gstart   = (int*)alloc((NG + 4) * 4);
  int*      hist     = (int*)alloc((size_t)NCH * NN * 4);
  int*      chunkoff = (int*)alloc((size_t)NCH * NN * 4);
  _Float16* hbf      = (_Float16*)alloc((size_t)5 * NE * HD * 2);
  _Float16* x16      = (_Float16*)alloc((size_t)NN * 16 * 2);
  _Float16* w2T0     = (_Float16*)alloc((size_t)128 * 2080 * 2);
  _Float16* w2T      = (_Float16*)alloc((size_t)4 * 128 * 16512 * 2);
  float*    hnA      = (float*)alloc((size_t)NN * HD * 4);
  float*    hnB      = (float*)alloc((size_t)NN * HD * 4);
  _Float16* hnAh     = (_Float16*)alloc((size_t)NN * HD * 2);
  _Float16* hnBh     = (_Float16*)alloc((size_t)NN * HD * 2);
  _Float16* msgp     = (_Float16*)alloc((size_t)SKM * NE * HD * 2);

  const int* src = eidx;
  const int* dstp = eidx + NE;

  hipMemsetAsync(hist, 0, (size_t)NCH * NN * 4, stream);
  k_prep<<<dim3(12576), 256, 0, stream>>>(ea, w1_0, b1_0, w1_s, b1_s, x,
                                          w2_0, b2_0, w2_s, b2_s,
                                          dstp, hist, hbf, x16, w2T0, w2T);
  k_scan2<<<1, 1024, 0, stream>>>(hist, rowptr, chunkoff, batch, gstart);
  k_fill2<<<dim3(NCH), 64, 0, stream>>>(dstp, chunkoff, elist);

  // layer 0
  k_mma0<<<dim3(NE / 128, SK0), 256, 0, stream>>>(x16, hbf, w2T0, src, msgp);
  k_au<11, SK0><<<NN, HD, 0, stream>>>(msgp, rowptr, elist, x, root_0, bias_0,
                                       bn_g0, bn_b0, bn_m0, bn_v0, nullptr, hnA, hnAh);

  float* cur = hnA;  _Float16* curh = hnAh;
  float* nxt = hnB;  _Float16* nxth = hnBh;
  for (int l = 1; l <= 4; ++l) {
    const _Float16* w2Tl = w2T + (size_t)(l - 1) * 128 * 16512;
    k_mma3<<<dim3(256), 512, 0, stream>>>(curh, hbf + (size_t)l * NE * HD, w2Tl, src, msgp);
    k_au<128, SKM><<<NN, HD, 0, stream>>>(msgp, rowptr, elist, cur,
                                          root_s + (size_t)(l - 1) * HD * HD,
                                          bias_s + (size_t)(l - 1) * HD,
                                          bn_gs + (size_t)(l - 1) * HD, bn_bs + (size_t)(l - 1) * HD,
                                          bn_ms + (size_t)(l - 1) * HD, bn_vs + (size_t)(l - 1) * HD,
                                          cur, nxt, nxth);
    float* tf = cur; cur = nxt; nxt = tf;
    _Float16* th = curh; curh = nxth; nxth = th;
  }

  k_poolread<<<NG, HD, 0, stream>>>(cur, gstart, lin1_w, lin1_b, lin2_w, lin2_b, out);
}